// Round 7
// baseline (810.625 us; speedup 1.0000x reference)
//
#include <hip/hip_runtime.h>
#include <cstdint>

constexpr int kHashSize = 1 << 17;
constexpr uint32_t kHashMask = (uint32_t)kHashSize - 1u;
constexpr int kBuckets = 32 * 32 * 32;  // spatial sort grid

typedef float f2 __attribute__((ext_vector_type(2)));
typedef float f4 __attribute__((ext_vector_type(4)));

// Static per-level resolutions: max(1, round(16 * b**l)), b = 16^(1/11)
__constant__ float kRes[12] = {16.f,  21.f,  26.f,  34.f,  44.f,  56.f,
                               73.f,  93.f,  120.f, 155.f, 199.f, 256.f};

// Level->group permutation: each XCD-pair group owns ONE fine level (no
// sort-dedup possible) + two coarse levels (nearly free after sorting).
// Deduped request cost/pt ~ {8.4, 8.6, 6.6, 4.8}; no-dedup worst case = 24
// for every group == the round-5 balance (floor-safe).
__constant__ int kGL[4][3] = {{0, 4, 11}, {1, 5, 10}, {2, 6, 9}, {3, 7, 8}};

// ---------- pass 0: zero histogram ----------
__global__ __launch_bounds__(256) void k_zero(uint32_t* hist) {
  int i = blockIdx.x * 256 + threadIdx.x;
  if (i < kBuckets) hist[i] = 0u;
}

// ---------- pass 1: bucket id + rank via atomic ----------
__global__ __launch_bounds__(256) void k_hist(const float* __restrict__ x,
                                              uint32_t* __restrict__ hist,
                                              uint32_t* __restrict__ cellbuf,
                                              uint32_t* __restrict__ rankbuf,
                                              int npts) {
  int n = blockIdx.x * 256 + threadIdx.x;
  if (n >= npts) return;
  float px = x[3 * n + 0], py = x[3 * n + 1], pz = x[3 * n + 2];
  uint32_t ix = (uint32_t)min(31, (int)(px * 32.f));
  uint32_t iy = (uint32_t)min(31, (int)(py * 32.f));
  uint32_t iz = (uint32_t)min(31, (int)(pz * 32.f));
  uint32_t cell = (ix << 10) | (iy << 5) | iz;
  uint32_t r = atomicAdd(&hist[cell], 1u);
  cellbuf[n] = cell;
  rankbuf[n] = r;
}

// ---------- pass 2: exclusive scan over 32768 counts (single block) ----------
__global__ __launch_bounds__(1024) void k_scan(uint32_t* __restrict__ hist) {
  __shared__ uint32_t lds[1024];
  const int t = threadIdx.x;
  uint32_t v[32];
  uint32_t s = 0;
#pragma unroll
  for (int i = 0; i < 32; ++i) {
    v[i] = hist[t * 32 + i];
    s += v[i];
  }
  lds[t] = s;
  __syncthreads();
  for (int off = 1; off < 1024; off <<= 1) {
    uint32_t add = (t >= off) ? lds[t - off] : 0u;
    __syncthreads();
    lds[t] += add;
    __syncthreads();
  }
  uint32_t run = lds[t] - s;  // exclusive base for this thread's 32 slots
#pragma unroll
  for (int i = 0; i < 32; ++i) {
    uint32_t c = v[i];
    hist[t * 32 + i] = run;
    run += c;
  }
}

// ---------- pass 3: scatter points into sorted order ----------
__global__ __launch_bounds__(256) void k_scatter(const float* __restrict__ x,
                                                 const uint32_t* __restrict__ offs,
                                                 const uint32_t* __restrict__ cellbuf,
                                                 const uint32_t* __restrict__ rankbuf,
                                                 f4* __restrict__ pts, int npts) {
  int n = blockIdx.x * 256 + threadIdx.x;
  if (n >= npts) return;
  uint32_t pos = offs[cellbuf[n]] + rankbuf[n];
  f4 p;
  p.x = x[3 * n + 0];
  p.y = x[3 * n + 1];
  p.z = x[3 * n + 2];
  p.w = __uint_as_float((uint32_t)n);
  __builtin_nontemporal_store(p, pts + pos);
}

// ---------- pass 4: main gather, sorted points, fine/coarse mixed groups ----
__global__ __launch_bounds__(256) void hashenc_sorted(
    const f4* __restrict__ pts,        // [N] sorted {x,y,z,orig}
    const float* __restrict__ tables,  // [12, 131072, 2]
    float* __restrict__ out,           // [N,12,2]
    int npts, int bpg) {
  const int b = blockIdx.x;
  const int c = b & 7;                        // XCD slot (round-robin, verified R5)
  const int g = c >> 1;                       // group 0..3
  const int sub = ((b >> 3) << 1) | (c & 1);  // block index within group
  if (sub >= bpg) return;
  const int n = sub * 256 + (int)threadIdx.x;
  if (n >= npts) return;

  const f4 p = pts[n];
  const float px = p.x, py = p.y, pz = p.z;
  const uint32_t orig = __float_as_uint(p.w);

  const f2* __restrict__ tbl2 = reinterpret_cast<const f2*>(tables);
  f2* __restrict__ out2 = reinterpret_cast<f2*>(out);

#pragma unroll
  for (int k = 0; k < 3; ++k) {
    const int l = kGL[g][k];
    const float r = kRes[l];
    const float xs = px * r, ys = py * r, zs = pz * r;
    const float fx = floorf(xs), fy = floorf(ys), fz = floorf(zs);
    const float wx = xs - fx, wy = ys - fy, wz = zs - fz;
    const uint32_t ix = (uint32_t)(int32_t)fx;
    const uint32_t iy = (uint32_t)(int32_t)fy;
    const uint32_t iz = (uint32_t)(int32_t)fz;

    // incremental spatial hash (uint32 wraparound == reference int32 semantics)
    const uint32_t hx0 = ix * 73856093u, hx1 = hx0 + 73856093u;
    const uint32_t hy0 = iy * 19349663u, hy1 = hy0 + 19349663u;
    const uint32_t hz0 = iz * 83492791u, hz1 = hz0 + 83492791u;

    const f2* __restrict__ t = tbl2 + (size_t)l * kHashSize;

    const f2 f000 = t[(hx0 ^ hy0 ^ hz0) & kHashMask];
    const f2 f001 = t[(hx0 ^ hy0 ^ hz1) & kHashMask];
    const f2 f010 = t[(hx0 ^ hy1 ^ hz0) & kHashMask];
    const f2 f011 = t[(hx0 ^ hy1 ^ hz1) & kHashMask];
    const f2 f100 = t[(hx1 ^ hy0 ^ hz0) & kHashMask];
    const f2 f101 = t[(hx1 ^ hy0 ^ hz1) & kHashMask];
    const f2 f110 = t[(hx1 ^ hy1 ^ hz0) & kHashMask];
    const f2 f111 = t[(hx1 ^ hy1 ^ hz1) & kHashMask];

    const float ax0 = 1.f - wx, ax1 = wx;
    const float by0 = 1.f - wy, by1 = wy;
    const float cz0 = 1.f - wz, cz1 = wz;
    const float ab00 = ax0 * by0, ab01 = ax0 * by1;
    const float ab10 = ax1 * by0, ab11 = ax1 * by1;
    const float w000 = ab00 * cz0, w001 = ab00 * cz1;
    const float w010 = ab01 * cz0, w011 = ab01 * cz1;
    const float w100 = ab10 * cz0, w101 = ab10 * cz1;
    const float w110 = ab11 * cz0, w111 = ab11 * cz1;

    f2 a;
    a.x = w000 * f000.x + w001 * f001.x + w010 * f010.x + w011 * f011.x +
          w100 * f100.x + w101 * f101.x + w110 * f110.x + w111 * f111.x;
    a.y = w000 * f000.y + w001 * f001.y + w010 * f010.y + w011 * f011.y +
          w100 * f100.y + w101 * f101.y + w110 * f110.y + w111 * f111.y;

    __builtin_nontemporal_store(a, out2 + (size_t)orig * 12 + l);
  }
}

// ---------- fallback (round-5 kernel) if ws too small ----------
__global__ __launch_bounds__(256) void hashenc_grouped(
    const float* __restrict__ x, const float* __restrict__ tables,
    float* __restrict__ out, int npts, int bpg) {
  const int b = blockIdx.x;
  const int c = b & 7;
  const int g = c >> 1;
  const int sub = ((b >> 3) << 1) | (c & 1);
  if (sub >= bpg) return;
  const int n = sub * 256 + (int)threadIdx.x;
  if (n >= npts) return;
  const float px = x[3 * n + 0], py = x[3 * n + 1], pz = x[3 * n + 2];
  const f2* __restrict__ tbl2 = reinterpret_cast<const f2*>(tables);
  f2 accv[3];
#pragma unroll
  for (int k = 0; k < 3; ++k) {
    const int l = 3 * g + k;
    const float r = kRes[l];
    const float xs = px * r, ys = py * r, zs = pz * r;
    const float fx = floorf(xs), fy = floorf(ys), fz = floorf(zs);
    const float wx = xs - fx, wy = ys - fy, wz = zs - fz;
    const uint32_t ix = (uint32_t)(int32_t)fx;
    const uint32_t iy = (uint32_t)(int32_t)fy;
    const uint32_t iz = (uint32_t)(int32_t)fz;
    const uint32_t hx0 = ix * 73856093u, hx1 = hx0 + 73856093u;
    const uint32_t hy0 = iy * 19349663u, hy1 = hy0 + 19349663u;
    const uint32_t hz0 = iz * 83492791u, hz1 = hz0 + 83492791u;
    const f2* __restrict__ t = tbl2 + (size_t)l * kHashSize;
    const f2 f000 = t[(hx0 ^ hy0 ^ hz0) & kHashMask];
    const f2 f001 = t[(hx0 ^ hy0 ^ hz1) & kHashMask];
    const f2 f010 = t[(hx0 ^ hy1 ^ hz0) & kHashMask];
    const f2 f011 = t[(hx0 ^ hy1 ^ hz1) & kHashMask];
    const f2 f100 = t[(hx1 ^ hy0 ^ hz0) & kHashMask];
    const f2 f101 = t[(hx1 ^ hy0 ^ hz1) & kHashMask];
    const f2 f110 = t[(hx1 ^ hy1 ^ hz0) & kHashMask];
    const f2 f111 = t[(hx1 ^ hy1 ^ hz1) & kHashMask];
    const float ax0 = 1.f - wx, ax1 = wx;
    const float by0 = 1.f - wy, by1 = wy;
    const float cz0 = 1.f - wz, cz1 = wz;
    const float ab00 = ax0 * by0, ab01 = ax0 * by1;
    const float ab10 = ax1 * by0, ab11 = ax1 * by1;
    const float w000 = ab00 * cz0, w001 = ab00 * cz1;
    const float w010 = ab01 * cz0, w011 = ab01 * cz1;
    const float w100 = ab10 * cz0, w101 = ab10 * cz1;
    const float w110 = ab11 * cz0, w111 = ab11 * cz1;
    f2 a;
    a.x = w000 * f000.x + w001 * f001.x + w010 * f010.x + w011 * f011.x +
          w100 * f100.x + w101 * f101.x + w110 * f110.x + w111 * f111.x;
    a.y = w000 * f000.y + w001 * f001.y + w010 * f010.y + w011 * f011.y +
          w100 * f100.y + w101 * f101.y + w110 * f110.y + w111 * f111.y;
    accv[k] = a;
  }
  f2* o = reinterpret_cast<f2*>(out + (size_t)n * 24 + g * 6);
  __builtin_nontemporal_store(accv[0], o + 0);
  __builtin_nontemporal_store(accv[1], o + 1);
  __builtin_nontemporal_store(accv[2], o + 2);
}

extern "C" void kernel_launch(void* const* d_in, const int* in_sizes, int n_in,
                              void* d_out, int out_size, void* d_ws, size_t ws_size,
                              hipStream_t stream) {
  const float* x = (const float*)d_in[0];
  const float* tables = (const float*)d_in[1];
  float* out = (float*)d_out;
  const int npts = in_sizes[0] / 3;
  const int nb = (npts + 255) / 256;        // point blocks
  const int bpg = nb;                       // blocks per level-group
  const int nblocks = 8 * ((bpg + 1) / 2);  // 8 XCD slots x ceil(bpg/2)

  const size_t npad = (size_t)nb * 256;
  // ws layout: hist @0 (pad to 1MB) | cell 4*npad | rank 4*npad | pts 16*npad
  const size_t off_cell = 1u << 20;
  const size_t off_rank = off_cell + 4 * npad;
  const size_t off_pts = off_cell + 8 * npad;
  const size_t need = off_cell + 24 * npad;

  if (ws_size >= need) {
    uint8_t* ws = (uint8_t*)d_ws;
    uint32_t* hist = (uint32_t*)ws;
    uint32_t* cellbuf = (uint32_t*)(ws + off_cell);
    uint32_t* rankbuf = (uint32_t*)(ws + off_rank);
    f4* pts = (f4*)(ws + off_pts);

    hipLaunchKernelGGL(k_zero, dim3((kBuckets + 255) / 256), dim3(256), 0,
                       stream, hist);
    hipLaunchKernelGGL(k_hist, dim3(nb), dim3(256), 0, stream, x, hist, cellbuf,
                       rankbuf, npts);
    hipLaunchKernelGGL(k_scan, dim3(1), dim3(1024), 0, stream, hist);
    hipLaunchKernelGGL(k_scatter, dim3(nb), dim3(256), 0, stream, x, hist,
                       cellbuf, rankbuf, pts, npts);
    hipLaunchKernelGGL(hashenc_sorted, dim3(nblocks), dim3(256), 0, stream, pts,
                       tables, out, npts, bpg);
  } else {
    hipLaunchKernelGGL(hashenc_grouped, dim3(nblocks), dim3(256), 0, stream, x,
                       tables, out, npts, bpg);
  }
}

// Round 8
// 516.384 us; speedup vs baseline: 1.5698x; 1.5698x over previous
//
#include <hip/hip_runtime.h>
#include <cstdint>

constexpr int kHashSize = 1 << 17;
constexpr uint32_t kHashMask = (uint32_t)kHashSize - 1u;
constexpr int kBuckets = 32 * 32 * 32;  // spatial sort grid

typedef float f2 __attribute__((ext_vector_type(2)));
typedef float f4 __attribute__((ext_vector_type(4)));

// ---------- pass 0: zero histogram ----------
__global__ __launch_bounds__(256) void k_zero(uint32_t* hist) {
  int i = blockIdx.x * 256 + threadIdx.x;
  if (i < kBuckets) hist[i] = 0u;
}

// ---------- pass 1: bucket id + rank via atomic ----------
__global__ __launch_bounds__(256) void k_hist(const float* __restrict__ x,
                                              uint32_t* __restrict__ hist,
                                              uint32_t* __restrict__ cellbuf,
                                              uint32_t* __restrict__ rankbuf,
                                              int npts) {
  int n = blockIdx.x * 256 + threadIdx.x;
  if (n >= npts) return;
  float px = x[3 * n + 0], py = x[3 * n + 1], pz = x[3 * n + 2];
  uint32_t ix = (uint32_t)min(31, (int)(px * 32.f));
  uint32_t iy = (uint32_t)min(31, (int)(py * 32.f));
  uint32_t iz = (uint32_t)min(31, (int)(pz * 32.f));
  uint32_t cell = (ix << 10) | (iy << 5) | iz;
  uint32_t r = atomicAdd(&hist[cell], 1u);
  cellbuf[n] = cell;
  rankbuf[n] = r;
}

// ---------- pass 2: exclusive scan over 32768 counts (single block) ----------
__global__ __launch_bounds__(1024) void k_scan(uint32_t* __restrict__ hist) {
  __shared__ uint32_t lds[1024];
  const int t = threadIdx.x;
  uint32_t v[32];
  uint32_t s = 0;
#pragma unroll
  for (int i = 0; i < 32; ++i) {
    v[i] = hist[t * 32 + i];
    s += v[i];
  }
  lds[t] = s;
  __syncthreads();
  for (int off = 1; off < 1024; off <<= 1) {
    uint32_t add = (t >= off) ? lds[t - off] : 0u;
    __syncthreads();
    lds[t] += add;
    __syncthreads();
  }
  uint32_t run = lds[t] - s;  // exclusive base for this thread's 32 slots
#pragma unroll
  for (int i = 0; i < 32; ++i) {
    uint32_t c = v[i];
    hist[t * 32 + i] = run;
    run += c;
  }
}

// ---------- pass 3: scatter points into sorted order ----------
// plain stores (no nt): pts is re-read immediately by the main kernel
__global__ __launch_bounds__(256) void k_scatter(const float* __restrict__ x,
                                                 const uint32_t* __restrict__ offs,
                                                 const uint32_t* __restrict__ cellbuf,
                                                 const uint32_t* __restrict__ rankbuf,
                                                 f4* __restrict__ pts, int npts) {
  int n = blockIdx.x * 256 + threadIdx.x;
  if (n >= npts) return;
  uint32_t pos = offs[cellbuf[n]] + rankbuf[n];
  f4 p;
  p.x = x[3 * n + 0];
  p.y = x[3 * n + 1];
  p.z = x[3 * n + 2];
  p.w = __uint_as_float((uint32_t)n);
  pts[pos] = p;
}

// ---------- pass 4: all 12 levels per thread, sorted points ----------
// Round-0 body (fully unrolled, static acc, 32 VGPR) + sorted input +
// full-record 96B scatter to out[orig] (6 nt float4 stores, 2 lines/pt).
__global__ __launch_bounds__(256) void hashenc_main(
    const f4* __restrict__ pts,        // [N] sorted {x,y,z,orig}
    const float* __restrict__ tables,  // [12, 131072, 2]
    float* __restrict__ out,           // [N,12,2]
    int npts) {
  const float kRes[12] = {16.f,  21.f,  26.f,  34.f,  44.f,  56.f,
                          73.f,  93.f,  120.f, 155.f, 199.f, 256.f};
  int n = blockIdx.x * 256 + threadIdx.x;
  if (n >= npts) return;

  const f4 p = pts[n];
  const float px = p.x, py = p.y, pz = p.z;
  const uint32_t orig = __float_as_uint(p.w);

  const f2* __restrict__ tbl2 = reinterpret_cast<const f2*>(tables);

  float acc[12][2];

#pragma unroll
  for (int l = 0; l < 12; ++l) {
    const float r = kRes[l];
    const float xs = px * r, ys = py * r, zs = pz * r;
    const float fx = floorf(xs), fy = floorf(ys), fz = floorf(zs);
    const float wx = xs - fx, wy = ys - fy, wz = zs - fz;
    const uint32_t ix = (uint32_t)(int32_t)fx;
    const uint32_t iy = (uint32_t)(int32_t)fy;
    const uint32_t iz = (uint32_t)(int32_t)fz;

    // incremental spatial hash (uint32 wraparound == reference int32 semantics)
    const uint32_t hx0 = ix * 73856093u, hx1 = hx0 + 73856093u;
    const uint32_t hy0 = iy * 19349663u, hy1 = hy0 + 19349663u;
    const uint32_t hz0 = iz * 83492791u, hz1 = hz0 + 83492791u;

    const f2* __restrict__ t = tbl2 + (size_t)l * kHashSize;

    const f2 f000 = t[(hx0 ^ hy0 ^ hz0) & kHashMask];
    const f2 f001 = t[(hx0 ^ hy0 ^ hz1) & kHashMask];
    const f2 f010 = t[(hx0 ^ hy1 ^ hz0) & kHashMask];
    const f2 f011 = t[(hx0 ^ hy1 ^ hz1) & kHashMask];
    const f2 f100 = t[(hx1 ^ hy0 ^ hz0) & kHashMask];
    const f2 f101 = t[(hx1 ^ hy0 ^ hz1) & kHashMask];
    const f2 f110 = t[(hx1 ^ hy1 ^ hz0) & kHashMask];
    const f2 f111 = t[(hx1 ^ hy1 ^ hz1) & kHashMask];

    const float ax0 = 1.f - wx, ax1 = wx;
    const float by0 = 1.f - wy, by1 = wy;
    const float cz0 = 1.f - wz, cz1 = wz;
    const float ab00 = ax0 * by0, ab01 = ax0 * by1;
    const float ab10 = ax1 * by0, ab11 = ax1 * by1;
    const float w000 = ab00 * cz0, w001 = ab00 * cz1;
    const float w010 = ab01 * cz0, w011 = ab01 * cz1;
    const float w100 = ab10 * cz0, w101 = ab10 * cz1;
    const float w110 = ab11 * cz0, w111 = ab11 * cz1;

    acc[l][0] = w000 * f000.x + w001 * f001.x + w010 * f010.x + w011 * f011.x +
                w100 * f100.x + w101 * f101.x + w110 * f110.x + w111 * f111.x;
    acc[l][1] = w000 * f000.y + w001 * f001.y + w010 * f010.y + w011 * f011.y +
                w100 * f100.y + w101 * f101.y + w110 * f110.y + w111 * f111.y;
  }

  // full 96B record to out[orig]: 6 nontemporal float4 stores (16B aligned)
  f4* o = reinterpret_cast<f4*>(out + (size_t)orig * 24);
#pragma unroll
  for (int k = 0; k < 6; ++k) {
    f4 v;
    v.x = acc[2 * k + 0][0];
    v.y = acc[2 * k + 0][1];
    v.z = acc[2 * k + 1][0];
    v.w = acc[2 * k + 1][1];
    __builtin_nontemporal_store(v, o + k);
  }
}

// ---------- fallback (round-5 kernel, 410us) if ws too small ----------
__global__ __launch_bounds__(256) void hashenc_grouped(
    const float* __restrict__ x, const float* __restrict__ tables,
    float* __restrict__ out, int npts, int bpg) {
  const float kRes[12] = {16.f,  21.f,  26.f,  34.f,  44.f,  56.f,
                          73.f,  93.f,  120.f, 155.f, 199.f, 256.f};
  const int b = blockIdx.x;
  const int c = b & 7;
  const int g = c >> 1;
  const int sub = ((b >> 3) << 1) | (c & 1);
  if (sub >= bpg) return;
  const int n = sub * 256 + (int)threadIdx.x;
  if (n >= npts) return;
  const float px = x[3 * n + 0], py = x[3 * n + 1], pz = x[3 * n + 2];
  const f2* __restrict__ tbl2 = reinterpret_cast<const f2*>(tables);
  f2 accv[3];
#pragma unroll
  for (int k = 0; k < 3; ++k) {
    const int l = 3 * g + k;
    const float r = kRes[l];
    const float xs = px * r, ys = py * r, zs = pz * r;
    const float fx = floorf(xs), fy = floorf(ys), fz = floorf(zs);
    const float wx = xs - fx, wy = ys - fy, wz = zs - fz;
    const uint32_t ix = (uint32_t)(int32_t)fx;
    const uint32_t iy = (uint32_t)(int32_t)fy;
    const uint32_t iz = (uint32_t)(int32_t)fz;
    const uint32_t hx0 = ix * 73856093u, hx1 = hx0 + 73856093u;
    const uint32_t hy0 = iy * 19349663u, hy1 = hy0 + 19349663u;
    const uint32_t hz0 = iz * 83492791u, hz1 = hz0 + 83492791u;
    const f2* __restrict__ t = tbl2 + (size_t)l * kHashSize;
    const f2 f000 = t[(hx0 ^ hy0 ^ hz0) & kHashMask];
    const f2 f001 = t[(hx0 ^ hy0 ^ hz1) & kHashMask];
    const f2 f010 = t[(hx0 ^ hy1 ^ hz0) & kHashMask];
    const f2 f011 = t[(hx0 ^ hy1 ^ hz1) & kHashMask];
    const f2 f100 = t[(hx1 ^ hy0 ^ hz0) & kHashMask];
    const f2 f101 = t[(hx1 ^ hy0 ^ hz1) & kHashMask];
    const f2 f110 = t[(hx1 ^ hy1 ^ hz0) & kHashMask];
    const f2 f111 = t[(hx1 ^ hy1 ^ hz1) & kHashMask];
    const float ax0 = 1.f - wx, ax1 = wx;
    const float by0 = 1.f - wy, by1 = wy;
    const float cz0 = 1.f - wz, cz1 = wz;
    const float ab00 = ax0 * by0, ab01 = ax0 * by1;
    const float ab10 = ax1 * by0, ab11 = ax1 * by1;
    const float w000 = ab00 * cz0, w001 = ab00 * cz1;
    const float w010 = ab01 * cz0, w011 = ab01 * cz1;
    const float w100 = ab10 * cz0, w101 = ab10 * cz1;
    const float w110 = ab11 * cz0, w111 = ab11 * cz1;
    f2 a;
    a.x = w000 * f000.x + w001 * f001.x + w010 * f010.x + w011 * f011.x +
          w100 * f100.x + w101 * f101.x + w110 * f110.x + w111 * f111.x;
    a.y = w000 * f000.y + w001 * f001.y + w010 * f010.y + w011 * f011.y +
          w100 * f100.y + w101 * f101.y + w110 * f110.y + w111 * f111.y;
    accv[k] = a;
  }
  f2* o = reinterpret_cast<f2*>(out + (size_t)n * 24 + g * 6);
  __builtin_nontemporal_store(accv[0], o + 0);
  __builtin_nontemporal_store(accv[1], o + 1);
  __builtin_nontemporal_store(accv[2], o + 2);
}

extern "C" void kernel_launch(void* const* d_in, const int* in_sizes, int n_in,
                              void* d_out, int out_size, void* d_ws, size_t ws_size,
                              hipStream_t stream) {
  const float* x = (const float*)d_in[0];
  const float* tables = (const float*)d_in[1];
  float* out = (float*)d_out;
  const int npts = in_sizes[0] / 3;
  const int nb = (npts + 255) / 256;  // point blocks

  const size_t npad = (size_t)nb * 256;
  // ws layout: hist @0 (pad to 1MB) | cell 4*npad | rank 4*npad | pts 16*npad
  const size_t off_cell = 1u << 20;
  const size_t off_rank = off_cell + 4 * npad;
  const size_t off_pts = off_cell + 8 * npad;
  const size_t need = off_cell + 24 * npad;

  if (ws_size >= need) {
    uint8_t* ws = (uint8_t*)d_ws;
    uint32_t* hist = (uint32_t*)ws;
    uint32_t* cellbuf = (uint32_t*)(ws + off_cell);
    uint32_t* rankbuf = (uint32_t*)(ws + off_rank);
    f4* pts = (f4*)(ws + off_pts);

    hipLaunchKernelGGL(k_zero, dim3((kBuckets + 255) / 256), dim3(256), 0,
                       stream, hist);
    hipLaunchKernelGGL(k_hist, dim3(nb), dim3(256), 0, stream, x, hist, cellbuf,
                       rankbuf, npts);
    hipLaunchKernelGGL(k_scan, dim3(1), dim3(1024), 0, stream, hist);
    hipLaunchKernelGGL(k_scatter, dim3(nb), dim3(256), 0, stream, x, hist,
                       cellbuf, rankbuf, pts, npts);
    hipLaunchKernelGGL(hashenc_main, dim3(nb), dim3(256), 0, stream, pts,
                       tables, out, npts);
  } else {
    const int bpg = nb;
    const int nblocks = 8 * ((bpg + 1) / 2);
    hipLaunchKernelGGL(hashenc_grouped, dim3(nblocks), dim3(256), 0, stream, x,
                       tables, out, npts, bpg);
  }
}